// Round 8
// baseline (1122.643 us; speedup 1.0000x reference)
//
#include <hip/hip_runtime.h>
#include <math.h>

// Problem constants (match reference)
#define N_PIX   262144
#define G_NUM   4096
#define K_FREQ  4
#define GSTRIDE 32      // floats per packed gaussian record (128 B)
#define BLOCK   256
#define GSPLIT  8       // gaussian-range split: 512-g work items for balancing
#define NBIN1   64      // spatial bins per axis (64x64 = 4096 bins, ~64 pts/bin)
#define NBINS   (NBIN1*NBIN1)
#define NGRP    (N_PIX / 64)       // 4096 wave-groups of 64 sorted pixels
#define NITEMS  (NGRP * GSPLIT)    // 32768 work items
#define NW      (G_NUM / GSPLIT / 64)  // 8 mask words per item
#define NPOOL   8                  // sharded ticket counters
#define NPP     (NITEMS / NPOOL)   // 4096 items per pool
#define GRID_PERS 2048             // 8 blocks/CU x 256 CU = exactly-capacity
#define GA_CUT  12.0f   // skip pair when min ga over group bbox > CUT (gw < 2^-12)

#if __has_builtin(__builtin_amdgcn_exp2f)
#define EXP2F(x) __builtin_amdgcn_exp2f(x)
#else
#define EXP2F(x) exp2f(x)
#endif

// cos(2*pi*v): v_cos_f32 takes revolutions; v_fract_f32 does range reduction.
__device__ __forceinline__ float cos2pi(float v) {
    return __builtin_amdgcn_cosf(__builtin_amdgcn_fractf(v));
}

// Pack per-gaussian params into a 32-float record:
// [0..3]  px, py, cos(rot), sin(rot)
// [4..7]  isx*S, isy*S, color0, color1      (S = sqrt(0.5*log2(e)))
// [8..10] color2, qxn, qyn   (qxn=-(gx*cr+gy*sr), qyn=gx*sr-gy*cr -> tx,ty via 2 fma)
// [12..15] fx[0..3]  [16..19] cx[0..3]  [20..23] fy[0..3]  [24..27] cy[0..3]
// Record G_NUM (index 4096) is all-zero: the DUMMY record used to pad the
// render loop's round-robin pipeline (colors=0 -> exact 0 contribution).
__global__ void prep_kernel(const float* __restrict__ colors,
                            const float* __restrict__ pos,
                            const float* __restrict__ scales,
                            const float* __restrict__ rots,
                            const float* __restrict__ coeffs,
                            const int*   __restrict__ idx,
                            float* __restrict__ gp)
{
    int g = blockIdx.x * blockDim.x + threadIdx.x;
    if (g > G_NUM) return;
    float* o = gp + (size_t)g * GSTRIDE;
    if (g == G_NUM) {
#pragma unroll
        for (int k = 0; k < GSTRIDE; ++k) o[k] = 0.f;
        return;
    }
    float sr, cr;
    sincosf(rots[g], &sr, &cr);
    const float SC = 0.84932180028801904f;   // sqrt(0.5 * log2(e))
    float isx = expf(scales[2*g + 0]) * SC;
    float isy = expf(scales[2*g + 1]) * SC;
    float gx = pos[2*g], gy = pos[2*g + 1];
    o[0] = gx;  o[1] = gy;  o[2] = cr;  o[3] = sr;
    o[4] = isx; o[5] = isy;
    o[6] = colors[3*g];  o[7] = colors[3*g + 1];
    o[8] = colors[3*g + 2];
    o[9]  = -(gx*cr + gy*sr);   // qxn
    o[10] =  (gx*sr - gy*cr);   // qyn
    o[11] = 0.f;
    const float FS = 1024.0f / 1024.0f;   // MAXF / NF
#pragma unroll
    for (int k = 0; k < K_FREQ; ++k) {
        o[12 + k] = (float)idx[g*2*K_FREQ + 2*k + 0] * FS;
        o[16 + k] = coeffs[g*2*K_FREQ + 2*k + 0];
        o[20 + k] = (float)idx[g*2*K_FREQ + 2*k + 1] * FS;
        o[24 + k] = coeffs[g*2*K_FREQ + 2*k + 1];
    }
    o[28] = 0.f; o[29] = 0.f; o[30] = 0.f; o[31] = 0.f;
}

__device__ __forceinline__ int bin_of(float2 P) {
    int bx = (int)(P.x * (float)NBIN1); bx = bx > NBIN1-1 ? NBIN1-1 : bx;
    int by = (int)(P.y * (float)NBIN1); by = by > NBIN1-1 ? NBIN1-1 : by;
    return by * NBIN1 + bx;
}

// --- counting sort of pixels into 64x64 spatial bins (3 tiny kernels) ---
__global__ void hist_kernel(const float2* __restrict__ x, int* __restrict__ hist)
{
    int i = blockIdx.x * blockDim.x + threadIdx.x;
    float2 P = x[i];
    atomicAdd(&hist[bin_of(P)], 1);
}

// Single-block Hillis-Steele inclusive scan over 4096 bins -> exclusive starts.
__global__ __launch_bounds__(1024) void scan_kernel(const int* __restrict__ hist,
                                                    int* __restrict__ start)
{
    __shared__ int s[NBINS];
    const int t = threadIdx.x;
    for (int k = t; k < NBINS; k += 1024) s[k] = hist[k];
    __syncthreads();
    for (int off = 1; off < NBINS; off <<= 1) {
        int v[4];
#pragma unroll
        for (int k = 0; k < 4; ++k) {
            int i = t + 1024*k;
            v[k] = (i >= off) ? s[i - off] : 0;
        }
        __syncthreads();
#pragma unroll
        for (int k = 0; k < 4; ++k) s[t + 1024*k] += v[k];
        __syncthreads();
    }
    for (int k = t; k < NBINS; k += 1024) start[k] = s[k] - hist[k];
}

__global__ void scatter_kernel(const float2* __restrict__ x,
                               const int* __restrict__ start,
                               int* __restrict__ cursor,
                               int* __restrict__ sidx,
                               float2* __restrict__ sx)
{
    int i = blockIdx.x * blockDim.x + threadIdx.x;
    float2 P = x[i];
    int b = bin_of(P);
    int pos = start[b] + atomicAdd(&cursor[b], 1);
    sidx[pos] = i;
    sx[pos]   = P;
}

// Per 64-pixel sorted group: conservative survivor bitmask over all 4096
// gaussians. Include gaussian iff min over the group's bbox of ga < GA_CUT.
// bbox-min is a lower bound on any pixel's ga, so exclusion implies the
// per-pixel weight would be < 2^-GA_CUT -> superset of exact survivors.
__global__ __launch_bounds__(BLOCK) void build_kernel(
    const float2* __restrict__ sx,
    const float*  __restrict__ gp,
    unsigned long long* __restrict__ wmask)
{
    const int lane = threadIdx.x & 63;
    const int grp  = blockIdx.x * (BLOCK/64) + (threadIdx.x >> 6);
    float2 P = sx[grp*64 + lane];

    float xmn = P.x, xmx = P.x, ymn = P.y, ymx = P.y;
    for (int m = 32; m; m >>= 1) {
        xmn = fminf(xmn, __shfl_xor(xmn, m));
        xmx = fmaxf(xmx, __shfl_xor(xmx, m));
        ymn = fminf(ymn, __shfl_xor(ymn, m));
        ymx = fmaxf(ymx, __shfl_xor(ymx, m));
    }
    const float cxp = 0.5f*(xmn + xmx), hx = 0.5f*(xmx - xmn);
    const float cyp = 0.5f*(ymn + ymx), hy = 0.5f*(ymx - ymn);

    const float4* q4 = (const float4*)gp;
    for (int w = 0; w < G_NUM/64; ++w) {
        const int gid = w*64 + lane;
        const float4* q = q4 + (size_t)gid * (GSTRIDE/4);
        const float4 A  = q[0];   // px, py, cr, sr
        const float4 Bv = q[1];   // isx', isy', c0, c1
        const float4 C2 = q[2];   // c2, qxn, qyn, -
        float acr = fabsf(A.z), asr = fabsf(A.w);
        float txc = fmaf(cxp, A.z, fmaf(cyp,  A.w, C2.y));
        float tyc = fmaf(cyp, A.z, fmaf(cxp, -A.w, C2.z));
        float rtx = fmaf(hx, acr, hy * asr);
        float rty = fmaf(hx, asr, hy * acr);
        float mtx = fmaxf(0.f, fabsf(txc) - rtx) * Bv.x;
        float mty = fmaxf(0.f, fabsf(tyc) - rty) * Bv.y;
        float gmin = fmaf(mty, mty, mtx * mtx);
        unsigned long long m = __ballot(gmin < GA_CUT);
        if (lane == 0) wmask[(size_t)grp * (G_NUM/64) + w] = m;
    }
}

// Bitmask walk over preloaded SGPR words; when the item is exhausted it
// returns G_NUM (the zeroed DUMMY record) so the caller needs no checks.
__device__ __forceinline__ int walk_next(
    int& wi, unsigned long long& word,
    unsigned long long m1, unsigned long long m2, unsigned long long m3,
    unsigned long long m4, unsigned long long m5, unsigned long long m6,
    unsigned long long m7, int gbase)
{
    for (;;) {
        if (word) {
            int b = (int)__builtin_ctzll(word);
            word &= word - 1;
            return gbase + wi * 64 + b;
        }
        if (++wi >= NW) return G_NUM;   // dummy
        word = (wi==1) ? m1 : (wi==2) ? m2 : (wi==3) ? m3 :
               (wi==4) ? m4 : (wi==5) ? m5 : (wi==6) ? m6 : m7;
    }
}

#define LOADREC(S, idx) do { \
    const float4* _q = q4 + (size_t)(idx) * (GSTRIDE/4); \
    S##_A = _q[0]; S##_B = _q[1]; S##_C = _q[2]; \
    S##_FX = _q[3]; S##_CX = _q[4]; S##_FY = _q[5]; S##_CY = _q[6]; } while (0)

#define BODY(S) do { \
    float tx = fmaf(P.x, S##_A.z, fmaf(P.y,  S##_A.w, S##_C.y)); \
    float ty = fmaf(P.y, S##_A.z, fmaf(P.x, -S##_A.w, S##_C.z)); \
    float bx = tx * S##_B.x, by = ty * S##_B.y; \
    float ga = fmaf(by, by, bx * bx); \
    float gw = EXP2F(-ga); \
    float wx = S##_CX.x * cos2pi(tx * S##_FX.x); \
    wx = fmaf(S##_CX.y, cos2pi(tx * S##_FX.y), wx); \
    wx = fmaf(S##_CX.z, cos2pi(tx * S##_FX.z), wx); \
    wx = fmaf(S##_CX.w, cos2pi(tx * S##_FX.w), wx); \
    float wy = S##_CY.x * cos2pi(ty * S##_FY.x); \
    wy = fmaf(S##_CY.y, cos2pi(ty * S##_FY.y), wy); \
    wy = fmaf(S##_CY.z, cos2pi(ty * S##_FY.z), wy); \
    wy = fmaf(S##_CY.w, cos2pi(ty * S##_FY.w), wy); \
    float w = (gw * wx) * wy; \
    ar = fmaf(w, S##_B.z, ar); \
    ag = fmaf(w, S##_B.w, ag); \
    ab = fmaf(w, S##_C.x, ab); } while (0)

// Persistent waves + sharded ticket pools (R5/R7 lessons: 8 counters on
// separate 512B lines; pool forced uniform via readfirstlane or the whole
// s_load pipeline demotes to VGPR (R6); pop issued at top, consumed at
// bottom). R8: (1) all NW mask words preloaded per item as 2x s_load_dwordx8
// -> walk transitions are s_cselect, no dependent s_loads; (2) 2-buffer
// round-robin record pipeline driven by popcount: BODY(R0);LOAD(R0);BODY(R1);
// LOAD(R1) -- removes the 28 s_mov rotation per survivor AND gives each
// record's 7 s_loads a full body (~146cy) + walk of slack before first use
// (R7 residual: ~26cy/survivor lgkmcnt stall, slack 146 < scalar-L2 ~170-200).
// Exhausted walks return the zeroed DUMMY record (exact +0 contribution).
__global__ __launch_bounds__(BLOCK) void render_kernel(
    const float2* __restrict__ sx,
    const int*    __restrict__ sidx,
    const float*  __restrict__ gp,
    const unsigned long long* __restrict__ wmask,
    int* __restrict__ ticket,
    float* __restrict__ out)
{
    const int lane = threadIdx.x & 63;
    const float4* __restrict__ q4 = (const float4*)gp;

    const int pool = __builtin_amdgcn_readfirstlane(
        (blockIdx.x * (BLOCK/64) + (threadIdx.x >> 6)) & (NPOOL - 1));
    int* __restrict__ tk = ticket + pool * 128;   // 512B-spaced counters

    int t0 = 0;
    if (lane == 0) t0 = atomicAdd(tk, 1);
    int t = __builtin_amdgcn_readfirstlane(t0);

    while (t < NPP) {
        // pop next ticket now; result consumed only at the bottom
        int t1 = 0;
        if (lane == 0) t1 = atomicAdd(tk, 1);

        const int item  = t * NPOOL + pool;
        const int grp   = item & (NGRP - 1);
        const int split = item >> 12;            // NGRP = 4096 = 2^12
        const int gbase = split * (G_NUM / GSPLIT);
        const unsigned long long* mw =
            wmask + (size_t)grp * (G_NUM/64) + split * NW;

        // preload all 8 mask words into SGPRs (2x s_load_dwordx8)
        const ulonglong4 mv0 = ((const ulonglong4*)mw)[0];
        const ulonglong4 mv1 = ((const ulonglong4*)mw)[1];
        const unsigned long long m0 = mv0.x, m1 = mv0.y, m2 = mv0.z, m3 = mv0.w;
        const unsigned long long m4 = mv1.x, m5 = mv1.y, m6 = mv1.z, m7 = mv1.w;
        const int cnt = __popcll(m0) + __popcll(m1) + __popcll(m2) + __popcll(m3)
                      + __popcll(m4) + __popcll(m5) + __popcll(m6) + __popcll(m7);

        const float2 P  = sx[grp*64 + lane];
        const int   pix = sidx[grp*64 + lane];

        float ar = 0.f, ag = 0.f, ab = 0.f;

        if (cnt > 0) {
            int wi = 0;
            unsigned long long word = m0;
            float4 R0_A, R0_B, R0_C, R0_FX, R0_CX, R0_FY, R0_CY;
            float4 R1_A, R1_B, R1_C, R1_FX, R1_CX, R1_FY, R1_CY;

            int ia = walk_next(wi, word, m1,m2,m3,m4,m5,m6,m7, gbase);
            LOADREC(R0, ia);
            int ib = walk_next(wi, word, m1,m2,m3,m4,m5,m6,m7, gbase);
            LOADREC(R1, ib);

            for (int r = cnt; r > 0; r -= 2) {
                BODY(R0);
                int i0 = walk_next(wi, word, m1,m2,m3,m4,m5,m6,m7, gbase);
                LOADREC(R0, i0);
                BODY(R1);
                int i1 = walk_next(wi, word, m1,m2,m3,m4,m5,m6,m7, gbase);
                LOADREC(R1, i1);
            }
        }

        const int o = pix * 3;
        atomicAdd(&out[o + 0], ar);
        atomicAdd(&out[o + 1], ag);
        atomicAdd(&out[o + 2], ab);

        // consume the pop issued at the top; waitcnt lands here, hidden
        t = __builtin_amdgcn_readfirstlane(t1);
    }
}

extern "C" void kernel_launch(void* const* d_in, const int* in_sizes, int n_in,
                              void* d_out, int out_size, void* d_ws, size_t ws_size,
                              hipStream_t stream) {
    const float* x      = (const float*)d_in[0];   // [N,2]
    const float* colors = (const float*)d_in[1];   // [G,3]
    const float* pos    = (const float*)d_in[2];   // [G,2]
    const float* scales = (const float*)d_in[3];   // [G,2]
    const float* rots   = (const float*)d_in[4];   // [G,1]
    const float* coeffs = (const float*)d_in[5];   // [G,K,2]
    const int*   idx    = (const int*)d_in[6];     // [G,K,2]
    float* out = (float*)d_out;

    // Workspace layout (needs ~5.6 MB):
    //   [0, 524416)       gp      4096 gaussian records + 1 DUMMY (zeroed)
    //   [524416, +16K)    hist    bin histogram   (memset each launch)
    //   [540800, +16K)    cursor  scatter cursors (memset each launch)
    //   [557184, +4K)     ticket  8 pool counters, 512B apart (memset)
    //   [561280, +16K)    start   exclusive bin starts
    //   [577664, +1M)     sidx    sorted -> original pixel index
    //   [1626240, +2M)    sx      sorted pixel coords (float2)
    //   [3723392, +2M)    wmask   per-group survivor bitmasks (4096 x 64 u64)
    char* ws = (char*)d_ws;
    float*  gp     = (float*)(ws);
    int*    hist   = (int*)(ws + 524416);
    int*    cursor = (int*)(ws + 540800);
    int*    ticket = (int*)(ws + 557184);
    int*    start  = (int*)(ws + 561280);
    int*    sidx   = (int*)(ws + 577664);
    float2* sx     = (float2*)(ws + 1626240);
    unsigned long long* wmask = (unsigned long long*)(ws + 3723392);

    prep_kernel<<<(G_NUM + 1 + 255) / 256, 256, 0, stream>>>(
        colors, pos, scales, rots, coeffs, idx, gp);

    // zero hist + cursor + tickets (adjacent, 36 KB) and the output
    hipMemsetAsync(hist, 0, 36864, stream);
    hipMemsetAsync(out, 0, (size_t)out_size * sizeof(float), stream);

    hist_kernel<<<N_PIX / 256, 256, 0, stream>>>((const float2*)x, hist);
    scan_kernel<<<1, 1024, 0, stream>>>(hist, start);
    scatter_kernel<<<N_PIX / 256, 256, 0, stream>>>((const float2*)x, start,
                                                    cursor, sidx, sx);
    build_kernel<<<NGRP / (BLOCK/64), BLOCK, 0, stream>>>(sx, gp, wmask);

    render_kernel<<<GRID_PERS, BLOCK, 0, stream>>>(sx, sidx, gp, wmask,
                                                   ticket, out);
}

// Round 9
// 943.989 us; speedup vs baseline: 1.1893x; 1.1893x over previous
//
#include <hip/hip_runtime.h>
#include <math.h>

// Problem constants (match reference)
#define N_PIX   262144
#define G_NUM   4096
#define K_FREQ  4
#define GSTRIDE 32      // floats per packed gaussian record (128 B)
#define BLOCK   256
#define GSPLIT  16      // 256-gaussian work items (keeps 4 items/wave balance)
#define NBIN1   64      // spatial bins per axis (64x64 = 4096 bins)
#define NBINS   (NBIN1*NBIN1)
#define PPG     128                // pixels per group (2 per lane)
#define NGRP    (N_PIX / PPG)      // 2048 groups
#define NITEMS  (NGRP * GSPLIT)    // 32768 work items
#define NW      (G_NUM / GSPLIT / 64)  // 4 mask words per item
#define NPOOL   8                  // sharded ticket counters
#define NPP     (NITEMS / NPOOL)   // 4096 items per pool
#define GRID_PERS 2048             // 8 blocks/CU x 256 CU = exactly-capacity
#define GA_CUT  12.0f   // skip pair when min ga over group bbox > CUT (gw < 2^-12)

#if __has_builtin(__builtin_amdgcn_exp2f)
#define EXP2F(x) __builtin_amdgcn_exp2f(x)
#else
#define EXP2F(x) exp2f(x)
#endif

// cos(2*pi*v): v_cos_f32 takes revolutions; v_fract_f32 does range reduction.
__device__ __forceinline__ float cos2pi(float v) {
    return __builtin_amdgcn_cosf(__builtin_amdgcn_fractf(v));
}

// Pack per-gaussian params into a 32-float record:
// [0..3]  px, py, cos(rot), sin(rot)
// [4..7]  isx*S, isy*S, color0, color1      (S = sqrt(0.5*log2(e)))
// [8..10] color2, qxn, qyn   (qxn=-(gx*cr+gy*sr), qyn=gx*sr-gy*cr -> tx,ty via 2 fma)
// [12..15] fx[0..3]  [16..19] cx[0..3]  [20..23] fy[0..3]  [24..27] cy[0..3]
__global__ void prep_kernel(const float* __restrict__ colors,
                            const float* __restrict__ pos,
                            const float* __restrict__ scales,
                            const float* __restrict__ rots,
                            const float* __restrict__ coeffs,
                            const int*   __restrict__ idx,
                            float* __restrict__ gp)
{
    int g = blockIdx.x * blockDim.x + threadIdx.x;
    if (g >= G_NUM) return;
    float sr, cr;
    sincosf(rots[g], &sr, &cr);
    const float SC = 0.84932180028801904f;   // sqrt(0.5 * log2(e))
    float isx = expf(scales[2*g + 0]) * SC;
    float isy = expf(scales[2*g + 1]) * SC;
    float gx = pos[2*g], gy = pos[2*g + 1];
    float* o = gp + (size_t)g * GSTRIDE;
    o[0] = gx;  o[1] = gy;  o[2] = cr;  o[3] = sr;
    o[4] = isx; o[5] = isy;
    o[6] = colors[3*g];  o[7] = colors[3*g + 1];
    o[8] = colors[3*g + 2];
    o[9]  = -(gx*cr + gy*sr);   // qxn
    o[10] =  (gx*sr - gy*cr);   // qyn
    o[11] = 0.f;
    const float FS = 1024.0f / 1024.0f;   // MAXF / NF
#pragma unroll
    for (int k = 0; k < K_FREQ; ++k) {
        o[12 + k] = (float)idx[g*2*K_FREQ + 2*k + 0] * FS;
        o[16 + k] = coeffs[g*2*K_FREQ + 2*k + 0];
        o[20 + k] = (float)idx[g*2*K_FREQ + 2*k + 1] * FS;
        o[24 + k] = coeffs[g*2*K_FREQ + 2*k + 1];
    }
    o[28] = 0.f; o[29] = 0.f; o[30] = 0.f; o[31] = 0.f;
}

__device__ __forceinline__ int bin_of(float2 P) {
    int bx = (int)(P.x * (float)NBIN1); bx = bx > NBIN1-1 ? NBIN1-1 : bx;
    int by = (int)(P.y * (float)NBIN1); by = by > NBIN1-1 ? NBIN1-1 : by;
    return by * NBIN1 + bx;
}

// --- counting sort of pixels into 64x64 spatial bins (3 tiny kernels) ---
__global__ void hist_kernel(const float2* __restrict__ x, int* __restrict__ hist)
{
    int i = blockIdx.x * blockDim.x + threadIdx.x;
    float2 P = x[i];
    atomicAdd(&hist[bin_of(P)], 1);
}

// Single-block Hillis-Steele inclusive scan over 4096 bins -> exclusive starts.
__global__ __launch_bounds__(1024) void scan_kernel(const int* __restrict__ hist,
                                                    int* __restrict__ start)
{
    __shared__ int s[NBINS];
    const int t = threadIdx.x;
    for (int k = t; k < NBINS; k += 1024) s[k] = hist[k];
    __syncthreads();
    for (int off = 1; off < NBINS; off <<= 1) {
        int v[4];
#pragma unroll
        for (int k = 0; k < 4; ++k) {
            int i = t + 1024*k;
            v[k] = (i >= off) ? s[i - off] : 0;
        }
        __syncthreads();
#pragma unroll
        for (int k = 0; k < 4; ++k) s[t + 1024*k] += v[k];
        __syncthreads();
    }
    for (int k = t; k < NBINS; k += 1024) start[k] = s[k] - hist[k];
}

__global__ void scatter_kernel(const float2* __restrict__ x,
                               const int* __restrict__ start,
                               int* __restrict__ cursor,
                               int* __restrict__ sidx,
                               float2* __restrict__ sx)
{
    int i = blockIdx.x * blockDim.x + threadIdx.x;
    float2 P = x[i];
    int b = bin_of(P);
    int pos = start[b] + atomicAdd(&cursor[b], 1);
    sidx[pos] = i;
    sx[pos]   = P;
}

// Per 128-pixel sorted group: conservative survivor bitmask over all 4096
// gaussians (bbox covers both pixels each lane owns). bbox-min is a lower
// bound on any pixel's ga, so exclusion implies per-pixel gw < 2^-GA_CUT.
// 128-px bbox >= 64-px bbox -> mask is a superset of R7's -> error <= R7's.
__global__ __launch_bounds__(BLOCK) void build_kernel(
    const float2* __restrict__ sx,
    const float*  __restrict__ gp,
    unsigned long long* __restrict__ wmask)
{
    const int lane = threadIdx.x & 63;
    const int grp  = blockIdx.x * (BLOCK/64) + (threadIdx.x >> 6);
    float2 Pa = sx[grp*PPG + lane];
    float2 Pb = sx[grp*PPG + 64 + lane];

    float xmn = fminf(Pa.x, Pb.x), xmx = fmaxf(Pa.x, Pb.x);
    float ymn = fminf(Pa.y, Pb.y), ymx = fmaxf(Pa.y, Pb.y);
    for (int m = 32; m; m >>= 1) {
        xmn = fminf(xmn, __shfl_xor(xmn, m));
        xmx = fmaxf(xmx, __shfl_xor(xmx, m));
        ymn = fminf(ymn, __shfl_xor(ymn, m));
        ymx = fmaxf(ymx, __shfl_xor(ymx, m));
    }
    const float cxp = 0.5f*(xmn + xmx), hx = 0.5f*(xmx - xmn);
    const float cyp = 0.5f*(ymn + ymx), hy = 0.5f*(ymx - ymn);

    const float4* q4 = (const float4*)gp;
    for (int w = 0; w < G_NUM/64; ++w) {
        const int gid = w*64 + lane;
        const float4* q = q4 + (size_t)gid * (GSTRIDE/4);
        const float4 A  = q[0];   // px, py, cr, sr
        const float4 Bv = q[1];   // isx', isy', c0, c1
        const float4 C2 = q[2];   // c2, qxn, qyn, -
        float acr = fabsf(A.z), asr = fabsf(A.w);
        float txc = fmaf(cxp, A.z, fmaf(cyp,  A.w, C2.y));
        float tyc = fmaf(cyp, A.z, fmaf(cxp, -A.w, C2.z));
        float rtx = fmaf(hx, acr, hy * asr);
        float rty = fmaf(hx, asr, hy * acr);
        float mtx = fmaxf(0.f, fabsf(txc) - rtx) * Bv.x;
        float mty = fmaxf(0.f, fabsf(tyc) - rty) * Bv.y;
        float gmin = fmaf(mty, mty, mtx * mtx);
        unsigned long long m = __ballot(gmin < GA_CUT);
        if (lane == 0) wmask[(size_t)grp * (G_NUM/64) + w] = m;
    }
}

// Walk over 4 preloaded SGPR mask words (select chain, no dependent s_loads);
// returns -1 when the item is exhausted.
__device__ __forceinline__ int walk_next4(
    int& wi, unsigned long long& word,
    unsigned long long m1, unsigned long long m2, unsigned long long m3,
    int gbase)
{
    for (;;) {
        if (word) {
            int b = (int)__builtin_ctzll(word);
            word &= word - 1;
            return gbase + wi * 64 + b;
        }
        if (++wi >= NW) return -1;
        word = (wi==1) ? m1 : (wi==2) ? m2 : m3;
    }
}

// Persistent waves + sharded ticket pools (R5-R7 lessons baked in: 8 pool
// counters on 512B lines; pool forced uniform via readfirstlane else the
// s_load pipeline demotes to VGPR; pop at top / consume at bottom).
// R9: TWO PIXELS PER LANE (128-px groups). Per-record VALU doubles while
// per-record overhead (walk, 7 s_load issues, rotation, lgkmcnt residual)
// is paid once -> amortized; the 2x body (~290cy) also exceeds scalar-L2
// latency (~200cy) so the R7 ~26cy/record stall disappears. R8 lesson:
// SGPR is the occupancy limiter (112 -> 7 waves/SIMD); here masks cost only
// 8 SGPRs (NW=4, one s_load_dwordx8) and the rotation pipeline stays at
// R7's ~80 -> 8 waves/SIMD preserved. GSPLIT=16 keeps 4 items/wave balance.
__global__ __launch_bounds__(BLOCK) void render_kernel(
    const float2* __restrict__ sx,
    const int*    __restrict__ sidx,
    const float*  __restrict__ gp,
    const unsigned long long* __restrict__ wmask,
    int* __restrict__ ticket,
    float* __restrict__ out)
{
    const int lane = threadIdx.x & 63;
    const float4* __restrict__ q4 = (const float4*)gp;

    const int pool = __builtin_amdgcn_readfirstlane(
        (blockIdx.x * (BLOCK/64) + (threadIdx.x >> 6)) & (NPOOL - 1));
    int* __restrict__ tk = ticket + pool * 128;   // 512B-spaced counters

    int t0 = 0;
    if (lane == 0) t0 = atomicAdd(tk, 1);
    int t = __builtin_amdgcn_readfirstlane(t0);

    while (t < NPP) {
        // pop next ticket now; result consumed only at the bottom
        int t1 = 0;
        if (lane == 0) t1 = atomicAdd(tk, 1);

        const int item  = t * NPOOL + pool;
        const int grp   = item & (NGRP - 1);
        const int split = item >> 11;            // NGRP = 2048 = 2^11
        const int gbase = split * (G_NUM / GSPLIT);
        const unsigned long long* mw =
            wmask + (size_t)grp * (G_NUM/64) + split * NW;

        // whole item mask in one s_load_dwordx8 (8 SGPRs)
        const ulonglong4 mv = ((const ulonglong4*)mw)[0];

        const float2 P0  = sx[grp*PPG + lane];
        const float2 P1  = sx[grp*PPG + 64 + lane];
        const int   pix0 = sidx[grp*PPG + lane];
        const int   pix1 = sidx[grp*PPG + 64 + lane];

        float ar0 = 0.f, ag0 = 0.f, ab0 = 0.f;
        float ar1 = 0.f, ag1 = 0.f, ab1 = 0.f;

        int wi = 0;
        unsigned long long word = mv.x;
        int cur = walk_next4(wi, word, mv.y, mv.z, mv.w, gbase);

        if (cur >= 0) {
            const float4* q = q4 + (size_t)cur * (GSTRIDE/4);
            float4 A  = q[0];
            float4 Bv = q[1];
            float4 C2 = q[2];
            float4 FX = q[3];
            float4 CX = q[4];
            float4 FY = q[5];
            float4 CY = q[6];

            for (;;) {
                int nxt = walk_next4(wi, word, mv.y, mv.z, mv.w, gbase);
                // prefetch next record (reload current on last iter; harmless)
                const int pidx = (nxt < 0) ? cur : nxt;
                const float4* qn = q4 + (size_t)pidx * (GSTRIDE/4);
                const float4 An  = qn[0];
                const float4 Bn  = qn[1];
                const float4 C2n = qn[2];
                const float4 FXn = qn[3];
                const float4 CXn = qn[4];
                const float4 FYn = qn[5];
                const float4 CYn = qn[6];

                // pixel 0
                float tx0 = fmaf(P0.x, A.z, fmaf(P0.y,  A.w, C2.y));
                float ty0 = fmaf(P0.y, A.z, fmaf(P0.x, -A.w, C2.z));
                float bx0 = tx0 * Bv.x, by0 = ty0 * Bv.y;
                float ga0 = fmaf(by0, by0, bx0 * bx0);
                float gw0 = EXP2F(-ga0);
                // pixel 1
                float tx1 = fmaf(P1.x, A.z, fmaf(P1.y,  A.w, C2.y));
                float ty1 = fmaf(P1.y, A.z, fmaf(P1.x, -A.w, C2.z));
                float bx1 = tx1 * Bv.x, by1 = ty1 * Bv.y;
                float ga1 = fmaf(by1, by1, bx1 * bx1);
                float gw1 = EXP2F(-ga1);

                float wx0, wx1;
                wx0  = CX.x * cos2pi(tx0 * FX.x);
                wx1  = CX.x * cos2pi(tx1 * FX.x);
                wx0  = fmaf(CX.y, cos2pi(tx0 * FX.y), wx0);
                wx1  = fmaf(CX.y, cos2pi(tx1 * FX.y), wx1);
                wx0  = fmaf(CX.z, cos2pi(tx0 * FX.z), wx0);
                wx1  = fmaf(CX.z, cos2pi(tx1 * FX.z), wx1);
                wx0  = fmaf(CX.w, cos2pi(tx0 * FX.w), wx0);
                wx1  = fmaf(CX.w, cos2pi(tx1 * FX.w), wx1);
                float wy0, wy1;
                wy0  = CY.x * cos2pi(ty0 * FY.x);
                wy1  = CY.x * cos2pi(ty1 * FY.x);
                wy0  = fmaf(CY.y, cos2pi(ty0 * FY.y), wy0);
                wy1  = fmaf(CY.y, cos2pi(ty1 * FY.y), wy1);
                wy0  = fmaf(CY.z, cos2pi(ty0 * FY.z), wy0);
                wy1  = fmaf(CY.z, cos2pi(ty1 * FY.z), wy1);
                wy0  = fmaf(CY.w, cos2pi(ty0 * FY.w), wy0);
                wy1  = fmaf(CY.w, cos2pi(ty1 * FY.w), wy1);

                float w0 = (gw0 * wx0) * wy0;
                float w1 = (gw1 * wx1) * wy1;
                ar0 = fmaf(w0, Bv.z, ar0);
                ag0 = fmaf(w0, Bv.w, ag0);
                ab0 = fmaf(w0, C2.x, ab0);
                ar1 = fmaf(w1, Bv.z, ar1);
                ag1 = fmaf(w1, Bv.w, ag1);
                ab1 = fmaf(w1, C2.x, ab1);

                if (nxt < 0) break;
                A = An; Bv = Bn; C2 = C2n; FX = FXn; CX = CXn; FY = FYn; CY = CYn;
                cur = nxt;
            }
        }

        const int o0 = pix0 * 3;
        atomicAdd(&out[o0 + 0], ar0);
        atomicAdd(&out[o0 + 1], ag0);
        atomicAdd(&out[o0 + 2], ab0);
        const int o1 = pix1 * 3;
        atomicAdd(&out[o1 + 0], ar1);
        atomicAdd(&out[o1 + 1], ag1);
        atomicAdd(&out[o1 + 2], ab1);

        // consume the pop issued at the top; waitcnt lands here, hidden
        t = __builtin_amdgcn_readfirstlane(t1);
    }
}

extern "C" void kernel_launch(void* const* d_in, const int* in_sizes, int n_in,
                              void* d_out, int out_size, void* d_ws, size_t ws_size,
                              hipStream_t stream) {
    const float* x      = (const float*)d_in[0];   // [N,2]
    const float* colors = (const float*)d_in[1];   // [G,3]
    const float* pos    = (const float*)d_in[2];   // [G,2]
    const float* scales = (const float*)d_in[3];   // [G,2]
    const float* rots   = (const float*)d_in[4];   // [G,1]
    const float* coeffs = (const float*)d_in[5];   // [G,K,2]
    const int*   idx    = (const int*)d_in[6];     // [G,K,2]
    float* out = (float*)d_out;

    // Workspace layout (needs ~4.7 MB):
    //   [0, 512K)          gp      gaussian records
    //   [512K, +16K)       hist    bin histogram   (memset each launch)
    //   [528K, +16K)       cursor  scatter cursors (memset each launch)
    //   [544K, +4K)        ticket  8 pool counters, 512B apart (memset)
    //   [548K, +16K)       start   exclusive bin starts
    //   [564K, +1M)        sidx    sorted -> original pixel index
    //   [564K+1M, +2M)     sx      sorted pixel coords (float2)
    //   [564K+3M, +1M)     wmask   per-group survivor bitmasks (2048 x 64 u64)
    char* ws = (char*)d_ws;
    float*  gp     = (float*)(ws);
    int*    hist   = (int*)(ws + 524288);
    int*    cursor = (int*)(ws + 524288 + 16384);
    int*    ticket = (int*)(ws + 524288 + 32768);
    int*    start  = (int*)(ws + 524288 + 36864);
    int*    sidx   = (int*)(ws + 524288 + 53248);
    float2* sx     = (float2*)(ws + 524288 + 53248 + 1048576);
    unsigned long long* wmask =
        (unsigned long long*)(ws + 524288 + 53248 + 1048576 + 2097152);

    prep_kernel<<<(G_NUM + 255) / 256, 256, 0, stream>>>(
        colors, pos, scales, rots, coeffs, idx, gp);

    // zero hist + cursor + tickets (adjacent, 36 KB) and the output
    hipMemsetAsync(hist, 0, 36864, stream);
    hipMemsetAsync(out, 0, (size_t)out_size * sizeof(float), stream);

    hist_kernel<<<N_PIX / 256, 256, 0, stream>>>((const float2*)x, hist);
    scan_kernel<<<1, 1024, 0, stream>>>(hist, start);
    scatter_kernel<<<N_PIX / 256, 256, 0, stream>>>((const float2*)x, start,
                                                    cursor, sidx, sx);
    build_kernel<<<NGRP / (BLOCK/64), BLOCK, 0, stream>>>(sx, gp, wmask);

    render_kernel<<<GRID_PERS, BLOCK, 0, stream>>>(sx, sidx, gp, wmask,
                                                   ticket, out);
}

// Round 10
// 898.024 us; speedup vs baseline: 1.2501x; 1.0512x over previous
//
#include <hip/hip_runtime.h>
#include <math.h>

// Problem constants (match reference)
#define N_PIX   262144
#define G_NUM   4096
#define K_FREQ  4
#define GSTRIDE 32      // floats per packed gaussian record (128 B)
#define BLOCK   256
#define GSPLIT  16      // 256-gaussian work items (keeps 4 items/wave balance)
#define NBIN1   64      // spatial bins per axis (64x64 = 4096 bins)
#define NBINS   (NBIN1*NBIN1)
#define PPG     128                // pixels per group (2 per lane)
#define NGRP    (N_PIX / PPG)      // 2048 groups
#define NITEMS  (NGRP * GSPLIT)    // 32768 work items
#define NW      (G_NUM / GSPLIT / 64)  // 4 mask words per item
#define NPOOL   8                  // sharded ticket counters
#define NPP     (NITEMS / NPOOL)   // 4096 items per pool
#define GRID_PERS 2048             // 8 blocks/CU x 256 CU = exactly-capacity
#define GA_CUT  12.0f   // skip pair when min ga over group bbox > CUT (gw < 2^-12)

#if __has_builtin(__builtin_amdgcn_exp2f)
#define EXP2F(x) __builtin_amdgcn_exp2f(x)
#else
#define EXP2F(x) exp2f(x)
#endif

// Packed-FP32 pair: half0 = pixel0, half1 = pixel1. <2 x float> arithmetic
// selects v_pk_{mul,add,fma}_f32 on gfx90a+ (gfx950 has HasPackedFP32Ops):
// one instruction = 2 FP32 ops/lane, halving the full-rate VALU stream.
typedef __attribute__((ext_vector_type(2))) float f32x2;

__device__ __forceinline__ f32x2 bc(float s) { return (f32x2){s, s}; }

// cos(2*pi*v) per half: v_fract range-reduce + v_cos (revolutions).
// No packed transcendentals exist; these stay per-half scalar ops.
__device__ __forceinline__ f32x2 cospk(f32x2 v) {
    f32x2 r;
    r.x = __builtin_amdgcn_cosf(__builtin_amdgcn_fractf(v.x));
    r.y = __builtin_amdgcn_cosf(__builtin_amdgcn_fractf(v.y));
    return r;
}

// cos(2*pi*v): v_cos_f32 takes revolutions; v_fract_f32 does range reduction.
__device__ __forceinline__ float cos2pi(float v) {
    return __builtin_amdgcn_cosf(__builtin_amdgcn_fractf(v));
}

// Pack per-gaussian params into a 32-float record:
// [0..3]  px, py, cos(rot), sin(rot)
// [4..7]  isx*S, isy*S, color0, color1      (S = sqrt(0.5*log2(e)))
// [8..10] color2, qxn, qyn   (qxn=-(gx*cr+gy*sr), qyn=gx*sr-gy*cr -> tx,ty via 2 fma)
// [12..15] fx[0..3]  [16..19] cx[0..3]  [20..23] fy[0..3]  [24..27] cy[0..3]
__global__ void prep_kernel(const float* __restrict__ colors,
                            const float* __restrict__ pos,
                            const float* __restrict__ scales,
                            const float* __restrict__ rots,
                            const float* __restrict__ coeffs,
                            const int*   __restrict__ idx,
                            float* __restrict__ gp)
{
    int g = blockIdx.x * blockDim.x + threadIdx.x;
    if (g >= G_NUM) return;
    float sr, cr;
    sincosf(rots[g], &sr, &cr);
    const float SC = 0.84932180028801904f;   // sqrt(0.5 * log2(e))
    float isx = expf(scales[2*g + 0]) * SC;
    float isy = expf(scales[2*g + 1]) * SC;
    float gx = pos[2*g], gy = pos[2*g + 1];
    float* o = gp + (size_t)g * GSTRIDE;
    o[0] = gx;  o[1] = gy;  o[2] = cr;  o[3] = sr;
    o[4] = isx; o[5] = isy;
    o[6] = colors[3*g];  o[7] = colors[3*g + 1];
    o[8] = colors[3*g + 2];
    o[9]  = -(gx*cr + gy*sr);   // qxn
    o[10] =  (gx*sr - gy*cr);   // qyn
    o[11] = 0.f;
    const float FS = 1024.0f / 1024.0f;   // MAXF / NF
#pragma unroll
    for (int k = 0; k < K_FREQ; ++k) {
        o[12 + k] = (float)idx[g*2*K_FREQ + 2*k + 0] * FS;
        o[16 + k] = coeffs[g*2*K_FREQ + 2*k + 0];
        o[20 + k] = (float)idx[g*2*K_FREQ + 2*k + 1] * FS;
        o[24 + k] = coeffs[g*2*K_FREQ + 2*k + 1];
    }
    o[28] = 0.f; o[29] = 0.f; o[30] = 0.f; o[31] = 0.f;
}

__device__ __forceinline__ int bin_of(float2 P) {
    int bx = (int)(P.x * (float)NBIN1); bx = bx > NBIN1-1 ? NBIN1-1 : bx;
    int by = (int)(P.y * (float)NBIN1); by = by > NBIN1-1 ? NBIN1-1 : by;
    return by * NBIN1 + bx;
}

// --- counting sort of pixels into 64x64 spatial bins (3 tiny kernels) ---
__global__ void hist_kernel(const float2* __restrict__ x, int* __restrict__ hist)
{
    int i = blockIdx.x * blockDim.x + threadIdx.x;
    float2 P = x[i];
    atomicAdd(&hist[bin_of(P)], 1);
}

// Single-block Hillis-Steele inclusive scan over 4096 bins -> exclusive starts.
__global__ __launch_bounds__(1024) void scan_kernel(const int* __restrict__ hist,
                                                    int* __restrict__ start)
{
    __shared__ int s[NBINS];
    const int t = threadIdx.x;
    for (int k = t; k < NBINS; k += 1024) s[k] = hist[k];
    __syncthreads();
    for (int off = 1; off < NBINS; off <<= 1) {
        int v[4];
#pragma unroll
        for (int k = 0; k < 4; ++k) {
            int i = t + 1024*k;
            v[k] = (i >= off) ? s[i - off] : 0;
        }
        __syncthreads();
#pragma unroll
        for (int k = 0; k < 4; ++k) s[t + 1024*k] += v[k];
        __syncthreads();
    }
    for (int k = t; k < NBINS; k += 1024) start[k] = s[k] - hist[k];
}

__global__ void scatter_kernel(const float2* __restrict__ x,
                               const int* __restrict__ start,
                               int* __restrict__ cursor,
                               int* __restrict__ sidx,
                               float2* __restrict__ sx)
{
    int i = blockIdx.x * blockDim.x + threadIdx.x;
    float2 P = x[i];
    int b = bin_of(P);
    int pos = start[b] + atomicAdd(&cursor[b], 1);
    sidx[pos] = i;
    sx[pos]   = P;
}

// Per 128-pixel sorted group: conservative survivor bitmask over all 4096
// gaussians (bbox covers both pixels each lane owns). bbox-min is a lower
// bound on any pixel's ga, so exclusion implies per-pixel gw < 2^-GA_CUT.
__global__ __launch_bounds__(BLOCK) void build_kernel(
    const float2* __restrict__ sx,
    const float*  __restrict__ gp,
    unsigned long long* __restrict__ wmask)
{
    const int lane = threadIdx.x & 63;
    const int grp  = blockIdx.x * (BLOCK/64) + (threadIdx.x >> 6);
    float2 Pa = sx[grp*PPG + lane];
    float2 Pb = sx[grp*PPG + 64 + lane];

    float xmn = fminf(Pa.x, Pb.x), xmx = fmaxf(Pa.x, Pb.x);
    float ymn = fminf(Pa.y, Pb.y), ymx = fmaxf(Pa.y, Pb.y);
    for (int m = 32; m; m >>= 1) {
        xmn = fminf(xmn, __shfl_xor(xmn, m));
        xmx = fmaxf(xmx, __shfl_xor(xmx, m));
        ymn = fminf(ymn, __shfl_xor(ymn, m));
        ymx = fmaxf(ymx, __shfl_xor(ymx, m));
    }
    const float cxp = 0.5f*(xmn + xmx), hx = 0.5f*(xmx - xmn);
    const float cyp = 0.5f*(ymn + ymx), hy = 0.5f*(ymx - ymn);

    const float4* q4 = (const float4*)gp;
    for (int w = 0; w < G_NUM/64; ++w) {
        const int gid = w*64 + lane;
        const float4* q = q4 + (size_t)gid * (GSTRIDE/4);
        const float4 A  = q[0];   // px, py, cr, sr
        const float4 Bv = q[1];   // isx', isy', c0, c1
        const float4 C2 = q[2];   // c2, qxn, qyn, -
        float acr = fabsf(A.z), asr = fabsf(A.w);
        float txc = fmaf(cxp, A.z, fmaf(cyp,  A.w, C2.y));
        float tyc = fmaf(cyp, A.z, fmaf(cxp, -A.w, C2.z));
        float rtx = fmaf(hx, acr, hy * asr);
        float rty = fmaf(hx, asr, hy * acr);
        float mtx = fmaxf(0.f, fabsf(txc) - rtx) * Bv.x;
        float mty = fmaxf(0.f, fabsf(tyc) - rty) * Bv.y;
        float gmin = fmaf(mty, mty, mtx * mtx);
        unsigned long long m = __ballot(gmin < GA_CUT);
        if (lane == 0) wmask[(size_t)grp * (G_NUM/64) + w] = m;
    }
}

// Walk over 4 preloaded SGPR mask words (select chain, no dependent s_loads);
// returns -1 when the item is exhausted.
__device__ __forceinline__ int walk_next4(
    int& wi, unsigned long long& word,
    unsigned long long m1, unsigned long long m2, unsigned long long m3,
    int gbase)
{
    for (;;) {
        if (word) {
            int b = (int)__builtin_ctzll(word);
            word &= word - 1;
            return gbase + wi * 64 + b;
        }
        if (++wi >= NW) return -1;
        word = (wi==1) ? m1 : (wi==2) ? m2 : m3;
    }
}

// Persistent waves + sharded ticket pools (R5-R7 lessons: 8 pool counters on
// 512B lines; pool forced uniform via readfirstlane else the s_load pipeline
// demotes to VGPR; pop at top / consume at bottom). R9: 2 pixels/lane
// amortizes per-record overhead. R10: the pixel-pair body is rewritten with
// <2 x float> (f32x2) so the backend emits packed v_pk_{fma,mul,add}_f32 --
// one instruction per 2 FP32 ops (gfx950 dual-pipe FP32; 157 TF peak is only
// reachable packed). Full-rate stream per record-iter: ~168cy -> ~68cy;
// transcendentals (fract/cos/exp, no packed form) unchanged. R8 lesson:
// SGPR is the occupancy limiter; masks = 8 SGPRs, rotation pipeline ~80.
__global__ __launch_bounds__(BLOCK) void render_kernel(
    const float2* __restrict__ sx,
    const int*    __restrict__ sidx,
    const float*  __restrict__ gp,
    const unsigned long long* __restrict__ wmask,
    int* __restrict__ ticket,
    float* __restrict__ out)
{
    const int lane = threadIdx.x & 63;
    const float4* __restrict__ q4 = (const float4*)gp;

    const int pool = __builtin_amdgcn_readfirstlane(
        (blockIdx.x * (BLOCK/64) + (threadIdx.x >> 6)) & (NPOOL - 1));
    int* __restrict__ tk = ticket + pool * 128;   // 512B-spaced counters

    int t0 = 0;
    if (lane == 0) t0 = atomicAdd(tk, 1);
    int t = __builtin_amdgcn_readfirstlane(t0);

    while (t < NPP) {
        // pop next ticket now; result consumed only at the bottom
        int t1 = 0;
        if (lane == 0) t1 = atomicAdd(tk, 1);

        const int item  = t * NPOOL + pool;
        const int grp   = item & (NGRP - 1);
        const int split = item >> 11;            // NGRP = 2048 = 2^11
        const int gbase = split * (G_NUM / GSPLIT);
        const unsigned long long* mw =
            wmask + (size_t)grp * (G_NUM/64) + split * NW;

        // whole item mask in one s_load_dwordx8 (8 SGPRs)
        const ulonglong4 mv = ((const ulonglong4*)mw)[0];

        const float2 P0  = sx[grp*PPG + lane];
        const float2 P1  = sx[grp*PPG + 64 + lane];
        const int   pix0 = sidx[grp*PPG + lane];
        const int   pix1 = sidx[grp*PPG + 64 + lane];

        const f32x2 Px = {P0.x, P1.x};
        const f32x2 Py = {P0.y, P1.y};

        f32x2 ar = {0.f, 0.f}, ag = {0.f, 0.f}, ab = {0.f, 0.f};

        int wi = 0;
        unsigned long long word = mv.x;
        int cur = walk_next4(wi, word, mv.y, mv.z, mv.w, gbase);

        if (cur >= 0) {
            const float4* q = q4 + (size_t)cur * (GSTRIDE/4);
            float4 A  = q[0];
            float4 Bv = q[1];
            float4 C2 = q[2];
            float4 FX = q[3];
            float4 CX = q[4];
            float4 FY = q[5];
            float4 CY = q[6];

            for (;;) {
                int nxt = walk_next4(wi, word, mv.y, mv.z, mv.w, gbase);
                // prefetch next record (reload current on last iter; harmless)
                const int pidx = (nxt < 0) ? cur : nxt;
                const float4* qn = q4 + (size_t)pidx * (GSTRIDE/4);
                const float4 An  = qn[0];
                const float4 Bn  = qn[1];
                const float4 C2n = qn[2];
                const float4 FXn = qn[3];
                const float4 CXn = qn[4];
                const float4 FYn = qn[5];
                const float4 CYn = qn[6];

                // packed pixel-pair body (contraction -> v_pk_fma_f32)
                f32x2 tx = Px * bc(A.z) + (Py * bc( A.w) + bc(C2.y));
                f32x2 ty = Py * bc(A.z) + (Px * bc(-A.w) + bc(C2.z));
                f32x2 bx = tx * bc(Bv.x);
                f32x2 by = ty * bc(Bv.y);
                f32x2 ga = bx * bx + by * by;
                f32x2 gw;
                gw.x = EXP2F(-ga.x);
                gw.y = EXP2F(-ga.y);

                f32x2 wx =      bc(CX.x) * cospk(tx * bc(FX.x));
                wx = wx + bc(CX.y) * cospk(tx * bc(FX.y));
                wx = wx + bc(CX.z) * cospk(tx * bc(FX.z));
                wx = wx + bc(CX.w) * cospk(tx * bc(FX.w));
                f32x2 wy =      bc(CY.x) * cospk(ty * bc(FY.x));
                wy = wy + bc(CY.y) * cospk(ty * bc(FY.y));
                wy = wy + bc(CY.z) * cospk(ty * bc(FY.z));
                wy = wy + bc(CY.w) * cospk(ty * bc(FY.w));

                f32x2 w = (gw * wx) * wy;
                ar = ar + w * bc(Bv.z);
                ag = ag + w * bc(Bv.w);
                ab = ab + w * bc(C2.x);

                if (nxt < 0) break;
                A = An; Bv = Bn; C2 = C2n; FX = FXn; CX = CXn; FY = FYn; CY = CYn;
                cur = nxt;
            }
        }

        const int o0 = pix0 * 3;
        atomicAdd(&out[o0 + 0], ar.x);
        atomicAdd(&out[o0 + 1], ag.x);
        atomicAdd(&out[o0 + 2], ab.x);
        const int o1 = pix1 * 3;
        atomicAdd(&out[o1 + 0], ar.y);
        atomicAdd(&out[o1 + 1], ag.y);
        atomicAdd(&out[o1 + 2], ab.y);

        // consume the pop issued at the top; waitcnt lands here, hidden
        t = __builtin_amdgcn_readfirstlane(t1);
    }
}

extern "C" void kernel_launch(void* const* d_in, const int* in_sizes, int n_in,
                              void* d_out, int out_size, void* d_ws, size_t ws_size,
                              hipStream_t stream) {
    const float* x      = (const float*)d_in[0];   // [N,2]
    const float* colors = (const float*)d_in[1];   // [G,3]
    const float* pos    = (const float*)d_in[2];   // [G,2]
    const float* scales = (const float*)d_in[3];   // [G,2]
    const float* rots   = (const float*)d_in[4];   // [G,1]
    const float* coeffs = (const float*)d_in[5];   // [G,K,2]
    const int*   idx    = (const int*)d_in[6];     // [G,K,2]
    float* out = (float*)d_out;

    // Workspace layout (needs ~4.7 MB):
    //   [0, 512K)          gp      gaussian records
    //   [512K, +16K)       hist    bin histogram   (memset each launch)
    //   [528K, +16K)       cursor  scatter cursors (memset each launch)
    //   [544K, +4K)        ticket  8 pool counters, 512B apart (memset)
    //   [548K, +16K)       start   exclusive bin starts
    //   [564K, +1M)        sidx    sorted -> original pixel index
    //   [564K+1M, +2M)     sx      sorted pixel coords (float2)
    //   [564K+3M, +1M)     wmask   per-group survivor bitmasks (2048 x 64 u64)
    char* ws = (char*)d_ws;
    float*  gp     = (float*)(ws);
    int*    hist   = (int*)(ws + 524288);
    int*    cursor = (int*)(ws + 524288 + 16384);
    int*    ticket = (int*)(ws + 524288 + 32768);
    int*    start  = (int*)(ws + 524288 + 36864);
    int*    sidx   = (int*)(ws + 524288 + 53248);
    float2* sx     = (float2*)(ws + 524288 + 53248 + 1048576);
    unsigned long long* wmask =
        (unsigned long long*)(ws + 524288 + 53248 + 1048576 + 2097152);

    prep_kernel<<<(G_NUM + 255) / 256, 256, 0, stream>>>(
        colors, pos, scales, rots, coeffs, idx, gp);

    // zero hist + cursor + tickets (adjacent, 36 KB) and the output
    hipMemsetAsync(hist, 0, 36864, stream);
    hipMemsetAsync(out, 0, (size_t)out_size * sizeof(float), stream);

    hist_kernel<<<N_PIX / 256, 256, 0, stream>>>((const float2*)x, hist);
    scan_kernel<<<1, 1024, 0, stream>>>(hist, start);
    scatter_kernel<<<N_PIX / 256, 256, 0, stream>>>((const float2*)x, start,
                                                    cursor, sidx, sx);
    build_kernel<<<NGRP / (BLOCK/64), BLOCK, 0, stream>>>(sx, gp, wmask);

    render_kernel<<<GRID_PERS, BLOCK, 0, stream>>>(sx, sidx, gp, wmask,
                                                   ticket, out);
}

// Round 12
// 873.774 us; speedup vs baseline: 1.2848x; 1.0278x over previous
//
#include <hip/hip_runtime.h>
#include <math.h>

// Problem constants (match reference)
#define N_PIX   262144
#define G_NUM   4096
#define K_FREQ  4
#define GSTRIDE 32      // floats per packed gaussian record (128 B)
#define BLOCK   256
#define GSPLIT  16      // 256-gaussian work items (keeps 4 items/wave balance)
#define NBIN1   64      // spatial bins per axis (64x64 = 4096 bins)
#define NBINS   (NBIN1*NBIN1)
#define PPG     128                // pixels per group (2 per lane)
#define NGRP    (N_PIX / PPG)      // 2048 groups
#define NITEMS  (NGRP * GSPLIT)    // 32768 work items
#define NW      (G_NUM / GSPLIT / 64)  // 4 mask words per item
#define NPOOL   8                  // sharded ticket counters
#define NPP     (NITEMS / NPOOL)   // 4096 items per pool
#define GRID_PERS 2048             // 8 blocks/CU x 256 CU = exactly-capacity
// R11: per-gaussian adaptive cull threshold. Keep gaussian g for a group iff
// min_ga(bbox) < cut_g, where cut_g = EPS_LOG + log2(B_g) and
// B_g = (sum|cx|)(sum|cy|)(max|color|). Dropped terms then satisfy
// |contribution| <= 2^-ga * B_g < 2^-EPS_LOG per channel -- a UNIFORM
// contribution bound (the old uniform GA_CUT=12 allowed up to 2^-12*B_g,
// i.e. worse error for large-B gaussians and wasted work on small-B ones).
#define EPS_LOG 17.0f   // per-term contribution bound 2^-17 ~ 7.6e-6
#define CUT_MAX 12.0f   // never keep less than the old GA_CUT=12 error level
#define CUT_MIN 5.0f

#if __has_builtin(__builtin_amdgcn_exp2f)
#define EXP2F(x) __builtin_amdgcn_exp2f(x)
#else
#define EXP2F(x) exp2f(x)
#endif

// Packed-FP32 pair: half0 = pixel0, half1 = pixel1. <2 x float> arithmetic
// selects v_pk_{mul,add,fma}_f32 on gfx90a+ (gfx950 has HasPackedFP32Ops):
// one instruction = 2 FP32 ops/lane, halving the full-rate VALU stream.
typedef __attribute__((ext_vector_type(2))) float f32x2;

__device__ __forceinline__ f32x2 bc(float s) { return (f32x2){s, s}; }

// cos(2*pi*v) per half: v_fract range-reduce + v_cos (revolutions).
// No packed transcendentals exist; these stay per-half scalar ops.
__device__ __forceinline__ f32x2 cospk(f32x2 v) {
    f32x2 r;
    r.x = __builtin_amdgcn_cosf(__builtin_amdgcn_fractf(v.x));
    r.y = __builtin_amdgcn_cosf(__builtin_amdgcn_fractf(v.y));
    return r;
}

// Pack per-gaussian params into a 32-float record:
// [0..3]  px, py, cos(rot), sin(rot)
// [4..7]  isx*S, isy*S, color0, color1      (S = sqrt(0.5*log2(e)))
// [8..11] color2, qxn, qyn, cut_g
// [12..15] fx[0..3]  [16..19] cx[0..3]  [20..23] fy[0..3]  [24..27] cy[0..3]
__global__ void prep_kernel(const float* __restrict__ colors,
                            const float* __restrict__ pos,
                            const float* __restrict__ scales,
                            const float* __restrict__ rots,
                            const float* __restrict__ coeffs,
                            const int*   __restrict__ idx,
                            float* __restrict__ gp)
{
    int g = blockIdx.x * blockDim.x + threadIdx.x;
    if (g >= G_NUM) return;
    float sr, cr;
    sincosf(rots[g], &sr, &cr);
    const float SC = 0.84932180028801904f;   // sqrt(0.5 * log2(e))
    float isx = expf(scales[2*g + 0]) * SC;
    float isy = expf(scales[2*g + 1]) * SC;
    float gx = pos[2*g], gy = pos[2*g + 1];
    float c0 = colors[3*g], c1 = colors[3*g + 1], c2 = colors[3*g + 2];
    float* o = gp + (size_t)g * GSTRIDE;
    o[0] = gx;  o[1] = gy;  o[2] = cr;  o[3] = sr;
    o[4] = isx; o[5] = isy;
    o[6] = c0;  o[7] = c1;
    o[8] = c2;
    o[9]  = -(gx*cr + gy*sr);   // qxn
    o[10] =  (gx*sr - gy*cr);   // qyn
    const float FS = 1024.0f / 1024.0f;   // MAXF / NF
    float sax = 0.f, say = 0.f;
#pragma unroll
    for (int k = 0; k < K_FREQ; ++k) {
        float cx = coeffs[g*2*K_FREQ + 2*k + 0];
        float cy = coeffs[g*2*K_FREQ + 2*k + 1];
        o[12 + k] = (float)idx[g*2*K_FREQ + 2*k + 0] * FS;
        o[16 + k] = cx;
        o[20 + k] = (float)idx[g*2*K_FREQ + 2*k + 1] * FS;
        o[24 + k] = cy;
        sax += fabsf(cx);
        say += fabsf(cy);
    }
    // per-gaussian adaptive cut: contribution bound B_g = sax*say*max|color|
    float mc = fmaxf(fabsf(c0), fmaxf(fabsf(c1), fabsf(c2)));
    float B  = sax * say * mc;
    float cut = EPS_LOG + log2f(B);          // log2f(0) = -inf -> clamped
    cut = fminf(CUT_MAX, fmaxf(CUT_MIN, cut));
    o[11] = cut;
    o[28] = 0.f; o[29] = 0.f; o[30] = 0.f; o[31] = 0.f;
}

__device__ __forceinline__ int bin_of(float2 P) {
    int bx = (int)(P.x * (float)NBIN1); bx = bx > NBIN1-1 ? NBIN1-1 : bx;
    int by = (int)(P.y * (float)NBIN1); by = by > NBIN1-1 ? NBIN1-1 : by;
    return by * NBIN1 + bx;
}

// --- counting sort of pixels into 64x64 spatial bins (3 tiny kernels) ---
__global__ void hist_kernel(const float2* __restrict__ x, int* __restrict__ hist)
{
    int i = blockIdx.x * blockDim.x + threadIdx.x;
    float2 P = x[i];
    atomicAdd(&hist[bin_of(P)], 1);
}

// Single-block Hillis-Steele inclusive scan over 4096 bins -> exclusive starts.
__global__ __launch_bounds__(1024) void scan_kernel(const int* __restrict__ hist,
                                                    int* __restrict__ start)
{
    __shared__ int s[NBINS];
    const int t = threadIdx.x;
    for (int k = t; k < NBINS; k += 1024) s[k] = hist[k];
    __syncthreads();
    for (int off = 1; off < NBINS; off <<= 1) {
        int v[4];
#pragma unroll
        for (int k = 0; k < 4; ++k) {
            int i = t + 1024*k;
            v[k] = (i >= off) ? s[i - off] : 0;
        }
        __syncthreads();
#pragma unroll
        for (int k = 0; k < 4; ++k) s[t + 1024*k] += v[k];
        __syncthreads();
    }
    for (int k = t; k < NBINS; k += 1024) start[k] = s[k] - hist[k];
}

__global__ void scatter_kernel(const float2* __restrict__ x,
                               const int* __restrict__ start,
                               int* __restrict__ cursor,
                               int* __restrict__ sidx,
                               float2* __restrict__ sx)
{
    int i = blockIdx.x * blockDim.x + threadIdx.x;
    float2 P = x[i];
    int b = bin_of(P);
    int pos = start[b] + atomicAdd(&cursor[b], 1);
    sidx[pos] = i;
    sx[pos]   = P;
}

// Per 128-pixel sorted group: conservative survivor bitmask over all 4096
// gaussians. Include gaussian iff min over the group's bbox of ga < cut_g
// (per-gaussian adaptive threshold from the record). bbox-min is a lower
// bound on any pixel's ga, so exclusion implies per-pixel contribution
// < 2^-EPS_LOG per channel.
__global__ __launch_bounds__(BLOCK) void build_kernel(
    const float2* __restrict__ sx,
    const float*  __restrict__ gp,
    unsigned long long* __restrict__ wmask)
{
    const int lane = threadIdx.x & 63;
    const int grp  = blockIdx.x * (BLOCK/64) + (threadIdx.x >> 6);
    float2 Pa = sx[grp*PPG + lane];
    float2 Pb = sx[grp*PPG + 64 + lane];

    float xmn = fminf(Pa.x, Pb.x), xmx = fmaxf(Pa.x, Pb.x);
    float ymn = fminf(Pa.y, Pb.y), ymx = fmaxf(Pa.y, Pb.y);
    for (int m = 32; m; m >>= 1) {
        xmn = fminf(xmn, __shfl_xor(xmn, m));
        xmx = fmaxf(xmx, __shfl_xor(xmx, m));
        ymn = fminf(ymn, __shfl_xor(ymn, m));
        ymx = fmaxf(ymx, __shfl_xor(ymx, m));
    }
    const float cxp = 0.5f*(xmn + xmx), hx = 0.5f*(xmx - xmn);
    const float cyp = 0.5f*(ymn + ymx), hy = 0.5f*(ymx - ymn);

    const float4* q4 = (const float4*)gp;
    for (int w = 0; w < G_NUM/64; ++w) {
        const int gid = w*64 + lane;
        const float4* q = q4 + (size_t)gid * (GSTRIDE/4);
        const float4 A  = q[0];   // px, py, cr, sr
        const float4 Bv = q[1];   // isx', isy', c0, c1
        const float4 C2 = q[2];   // c2, qxn, qyn, cut_g
        float acr = fabsf(A.z), asr = fabsf(A.w);
        float txc = fmaf(cxp, A.z, fmaf(cyp,  A.w, C2.y));
        float tyc = fmaf(cyp, A.z, fmaf(cxp, -A.w, C2.z));
        float rtx = fmaf(hx, acr, hy * asr);
        float rty = fmaf(hx, asr, hy * acr);
        float mtx = fmaxf(0.f, fabsf(txc) - rtx) * Bv.x;
        float mty = fmaxf(0.f, fabsf(tyc) - rty) * Bv.y;
        float gmin = fmaf(mty, mty, mtx * mtx);
        unsigned long long m = __ballot(gmin < C2.w);
        if (lane == 0) wmask[(size_t)grp * (G_NUM/64) + w] = m;
    }
}

// Walk over 4 preloaded SGPR mask words (select chain, no dependent s_loads);
// returns -1 when the item is exhausted.
__device__ __forceinline__ int walk_next4(
    int& wi, unsigned long long& word,
    unsigned long long m1, unsigned long long m2, unsigned long long m3,
    int gbase)
{
    for (;;) {
        if (word) {
            int b = (int)__builtin_ctzll(word);
            word &= word - 1;
            return gbase + wi * 64 + b;
        }
        if (++wi >= NW) return -1;
        word = (wi==1) ? m1 : (wi==2) ? m2 : m3;
    }
}

// Persistent waves + sharded ticket pools (R5-R7 lessons: 8 pool counters on
// 512B lines; pool forced uniform via readfirstlane else the s_load pipeline
// demotes to VGPR; pop at top / consume at bottom). R9: 2 pixels/lane
// amortizes per-record overhead. R10: packed f32x2 body (v_pk_fma_f32).
// R11: unchanged -- survivor-count reduction happens in prep/build.
__global__ __launch_bounds__(BLOCK) void render_kernel(
    const float2* __restrict__ sx,
    const int*    __restrict__ sidx,
    const float*  __restrict__ gp,
    const unsigned long long* __restrict__ wmask,
    int* __restrict__ ticket,
    float* __restrict__ out)
{
    const int lane = threadIdx.x & 63;
    const float4* __restrict__ q4 = (const float4*)gp;

    const int pool = __builtin_amdgcn_readfirstlane(
        (blockIdx.x * (BLOCK/64) + (threadIdx.x >> 6)) & (NPOOL - 1));
    int* __restrict__ tk = ticket + pool * 128;   // 512B-spaced counters

    int t0 = 0;
    if (lane == 0) t0 = atomicAdd(tk, 1);
    int t = __builtin_amdgcn_readfirstlane(t0);

    while (t < NPP) {
        // pop next ticket now; result consumed only at the bottom
        int t1 = 0;
        if (lane == 0) t1 = atomicAdd(tk, 1);

        const int item  = t * NPOOL + pool;
        const int grp   = item & (NGRP - 1);
        const int split = item >> 11;            // NGRP = 2048 = 2^11
        const int gbase = split * (G_NUM / GSPLIT);
        const unsigned long long* mw =
            wmask + (size_t)grp * (G_NUM/64) + split * NW;

        // whole item mask in one s_load_dwordx8 (8 SGPRs)
        const ulonglong4 mv = ((const ulonglong4*)mw)[0];

        const float2 P0  = sx[grp*PPG + lane];
        const float2 P1  = sx[grp*PPG + 64 + lane];
        const int   pix0 = sidx[grp*PPG + lane];
        const int   pix1 = sidx[grp*PPG + 64 + lane];

        const f32x2 Px = {P0.x, P1.x};
        const f32x2 Py = {P0.y, P1.y};

        f32x2 ar = {0.f, 0.f}, ag = {0.f, 0.f}, ab = {0.f, 0.f};

        int wi = 0;
        unsigned long long word = mv.x;
        int cur = walk_next4(wi, word, mv.y, mv.z, mv.w, gbase);

        if (cur >= 0) {
            const float4* q = q4 + (size_t)cur * (GSTRIDE/4);
            float4 A  = q[0];
            float4 Bv = q[1];
            float4 C2 = q[2];
            float4 FX = q[3];
            float4 CX = q[4];
            float4 FY = q[5];
            float4 CY = q[6];

            for (;;) {
                int nxt = walk_next4(wi, word, mv.y, mv.z, mv.w, gbase);
                // prefetch next record (reload current on last iter; harmless)
                const int pidx = (nxt < 0) ? cur : nxt;
                const float4* qn = q4 + (size_t)pidx * (GSTRIDE/4);
                const float4 An  = qn[0];
                const float4 Bn  = qn[1];
                const float4 C2n = qn[2];
                const float4 FXn = qn[3];
                const float4 CXn = qn[4];
                const float4 FYn = qn[5];
                const float4 CYn = qn[6];

                // packed pixel-pair body (contraction -> v_pk_fma_f32)
                f32x2 tx = Px * bc(A.z) + (Py * bc( A.w) + bc(C2.y));
                f32x2 ty = Py * bc(A.z) + (Px * bc(-A.w) + bc(C2.z));
                f32x2 bx = tx * bc(Bv.x);
                f32x2 by = ty * bc(Bv.y);
                f32x2 ga = bx * bx + by * by;
                f32x2 gw;
                gw.x = EXP2F(-ga.x);
                gw.y = EXP2F(-ga.y);

                f32x2 wx =      bc(CX.x) * cospk(tx * bc(FX.x));
                wx = wx + bc(CX.y) * cospk(tx * bc(FX.y));
                wx = wx + bc(CX.z) * cospk(tx * bc(FX.z));
                wx = wx + bc(CX.w) * cospk(tx * bc(FX.w));
                f32x2 wy =      bc(CY.x) * cospk(ty * bc(FY.x));
                wy = wy + bc(CY.y) * cospk(ty * bc(FY.y));
                wy = wy + bc(CY.z) * cospk(ty * bc(FY.z));
                wy = wy + bc(CY.w) * cospk(ty * bc(FY.w));

                f32x2 w = (gw * wx) * wy;
                ar = ar + w * bc(Bv.z);
                ag = ag + w * bc(Bv.w);
                ab = ab + w * bc(C2.x);

                if (nxt < 0) break;
                A = An; Bv = Bn; C2 = C2n; FX = FXn; CX = CXn; FY = FYn; CY = CYn;
                cur = nxt;
            }
        }

        const int o0 = pix0 * 3;
        atomicAdd(&out[o0 + 0], ar.x);
        atomicAdd(&out[o0 + 1], ag.x);
        atomicAdd(&out[o0 + 2], ab.x);
        const int o1 = pix1 * 3;
        atomicAdd(&out[o1 + 0], ar.y);
        atomicAdd(&out[o1 + 1], ag.y);
        atomicAdd(&out[o1 + 2], ab.y);

        // consume the pop issued at the top; waitcnt lands here, hidden
        t = __builtin_amdgcn_readfirstlane(t1);
    }
}

extern "C" void kernel_launch(void* const* d_in, const int* in_sizes, int n_in,
                              void* d_out, int out_size, void* d_ws, size_t ws_size,
                              hipStream_t stream) {
    const float* x      = (const float*)d_in[0];   // [N,2]
    const float* colors = (const float*)d_in[1];   // [G,3]
    const float* pos    = (const float*)d_in[2];   // [G,2]
    const float* scales = (const float*)d_in[3];   // [G,2]
    const float* rots   = (const float*)d_in[4];   // [G,1]
    const float* coeffs = (const float*)d_in[5];   // [G,K,2]
    const int*   idx    = (const int*)d_in[6];     // [G,K,2]
    float* out = (float*)d_out;

    // Workspace layout (needs ~4.7 MB):
    //   [0, 512K)          gp      gaussian records
    //   [512K, +16K)       hist    bin histogram   (memset each launch)
    //   [528K, +16K)       cursor  scatter cursors (memset each launch)
    //   [544K, +4K)        ticket  8 pool counters, 512B apart (memset)
    //   [548K, +16K)       start   exclusive bin starts
    //   [564K, +1M)        sidx    sorted -> original pixel index
    //   [564K+1M, +2M)     sx      sorted pixel coords (float2)
    //   [564K+3M, +1M)     wmask   per-group survivor bitmasks (2048 x 64 u64)
    char* ws = (char*)d_ws;
    float*  gp     = (float*)(ws);
    int*    hist   = (int*)(ws + 524288);
    int*    cursor = (int*)(ws + 524288 + 16384);
    int*    ticket = (int*)(ws + 524288 + 32768);
    int*    start  = (int*)(ws + 524288 + 36864);
    int*    sidx   = (int*)(ws + 524288 + 53248);
    float2* sx     = (float2*)(ws + 524288 + 53248 + 1048576);
    unsigned long long* wmask =
        (unsigned long long*)(ws + 524288 + 53248 + 1048576 + 2097152);

    prep_kernel<<<(G_NUM + 255) / 256, 256, 0, stream>>>(
        colors, pos, scales, rots, coeffs, idx, gp);

    // zero hist + cursor + tickets (adjacent, 36 KB) and the output
    hipMemsetAsync(hist, 0, 36864, stream);
    hipMemsetAsync(out, 0, (size_t)out_size * sizeof(float), stream);

    hist_kernel<<<N_PIX / 256, 256, 0, stream>>>((const float2*)x, hist);
    scan_kernel<<<1, 1024, 0, stream>>>(hist, start);
    scatter_kernel<<<N_PIX / 256, 256, 0, stream>>>((const float2*)x, start,
                                                    cursor, sidx, sx);
    build_kernel<<<NGRP / (BLOCK/64), BLOCK, 0, stream>>>(sx, gp, wmask);

    render_kernel<<<GRID_PERS, BLOCK, 0, stream>>>(sx, sidx, gp, wmask,
                                                   ticket, out);
}